// Round 10
// baseline (203.132 us; speedup 1.0000x reference)
//
#include <hip/hip_runtime.h>
#include <hip/hip_bf16.h>
#include <math.h>

#define F 128
#define PN_EPS 1e-5f
#define PN_SCALE 1.0f
#define GBM 64           // rows per block in MFMA GEMM
#define SHIFT 8          // nodes per dst-bucket = 256
#define CHUNK 8192       // edges per partition block
#define WFIX 4194304.0f  // 2^22 fixed-point scale for per-node weight sums
#define AGG_BLOCKS 2048
#define BCAP 6144        // LDS edge staging capacity in bucket_csr (48KB)

using short8 = __attribute__((ext_vector_type(8))) short;
using f32x4  = __attribute__((ext_vector_type(4))) float;

__device__ __forceinline__ unsigned short bf16_rne(float f) {
    union { float f; unsigned u; } v; v.f = f;
    unsigned r = v.u + 0x7fff + ((v.u >> 16) & 1);
    return (unsigned short)(r >> 16);
}

// P1: per-chunk bucket histogram -> part_cnt[bucket][chunk]  (no global atomics).
// First 64 blocks also transpose W -> wt bf16 (fused, saves a launch).
__global__ __launch_bounds__(256) void bucket_count(const int* __restrict__ dst,
                                                    int* __restrict__ part_cnt,
                                                    const float* __restrict__ W,
                                                    unsigned short* __restrict__ wt,
                                                    int E, int nbk, int np2) {
    if (blockIdx.x < 64) {
        int idx = blockIdx.x * 256 + threadIdx.x;  // 0..16383
        int k = idx >> 7;
        int col = idx & 127;
        wt[col * F + k] = bf16_rne(W[idx]);
    }
    __shared__ int lcnt[512];
    for (int i = threadIdx.x; i < nbk; i += 256) lcnt[i] = 0;
    __syncthreads();
    int base = blockIdx.x * CHUNK;
    int end = min(base + CHUNK, E);
    for (int e = base + threadIdx.x; e < end; e += 256)
        atomicAdd(&lcnt[dst[e] >> SHIFT], 1);
    __syncthreads();
    for (int i = threadIdx.x; i < nbk; i += 256)
        part_cnt[(size_t)i * np2 + blockIdx.x] = lcnt[i];  // transposed: [bucket][chunk]
}

// S1: one block per bucket: parallel-reduce its contiguous row -> bucket_tot[b]
__global__ __launch_bounds__(256) void bucket_totk(const int* __restrict__ part_cnt,
                                                   int* __restrict__ bucket_tot, int np2) {
    const int* row = part_cnt + (size_t)blockIdx.x * np2;
    int s = 0;
    for (int i = threadIdx.x; i < np2; i += 256) s += row[i];
    __shared__ int r[256];
    r[threadIdx.x] = s;
    __syncthreads();
    for (int off = 128; off >= 1; off >>= 1) {
        if (threadIdx.x < off) r[threadIdx.x] += r[threadIdx.x + off];
        __syncthreads();
    }
    if (threadIdx.x == 0) bucket_tot[blockIdx.x] = r[0];
}

// S2: single block LDS exclusive scan of bucket_tot[0..nbk) -> bucket_start
__global__ __launch_bounds__(512) void bucket_startk(const int* __restrict__ bucket_tot,
                                                     int* __restrict__ bucket_start, int nbk) {
    __shared__ int s[512];
    int t = threadIdx.x;
    int v = (t < nbk) ? bucket_tot[t] : 0;
    s[t] = v;
    __syncthreads();
    for (int off = 1; off < 512; off <<= 1) {
        int u = (t >= off) ? s[t - off] : 0;
        __syncthreads();
        s[t] += u;
        __syncthreads();
    }
    if (t < nbk) bucket_start[t] = s[t] - v;
}

// S3: one block per bucket: LDS exclusive scan of its chunk-count row (np2<=256),
// add bucket_start[b], write back as per-chunk write bases.
__global__ __launch_bounds__(256) void chunk_bases(int* __restrict__ part_cnt,
                                                   const int* __restrict__ bucket_start,
                                                   int np2) {
    __shared__ int s[256];
    int* row = part_cnt + (size_t)blockIdx.x * np2;
    int t = threadIdx.x;
    int v = (t < np2) ? row[t] : 0;
    s[t] = v;
    __syncthreads();
    for (int off = 1; off < 256; off <<= 1) {
        int u = (t >= off) ? s[t - off] : 0;
        __syncthreads();
        s[t] += u;
        __syncthreads();
    }
    if (t < np2) row[t] = bucket_start[blockIdx.x] + s[t] - v;
}

// P2: partition edges into bucket-contiguous part[] = {src | dlow<<17, w_bits}
__global__ __launch_bounds__(256) void partition_edges(
    const int* __restrict__ src, const int* __restrict__ dst,
    const float* __restrict__ ew, const int* __restrict__ part_cnt,
    uint2* __restrict__ part, int E, int nbk, int np2) {
    __shared__ int cur[512];
    for (int i = threadIdx.x; i < nbk; i += 256)
        cur[i] = part_cnt[(size_t)i * np2 + blockIdx.x];
    __syncthreads();
    int base = blockIdx.x * CHUNK;
    int end = min(base + CHUNK, E);
    for (int e = base + threadIdx.x; e < end; e += 256) {
        int d = dst[e];
        int b = d >> SHIFT;
        int pos = atomicAdd(&cur[b], 1);
        part[pos] = make_uint2((unsigned)src[e] | ((unsigned)(d & 255) << 17),
                               __float_as_uint(ew[e]));
    }
}

// P3: one block per bucket. Edges staged in LDS (single global read), per-node
// count + weight-sum via LDS atomics, LDS scan -> row_start/cnt/dis, scatter
// from LDS to csr={src, w}. Fallback to 2-pass global path if bucket > BCAP.
__global__ __launch_bounds__(256) void bucket_csr(
    const uint2* __restrict__ part, const int* __restrict__ bucket_start,
    const int* __restrict__ bucket_tot, uint2* __restrict__ csr,
    float* __restrict__ dis, int* __restrict__ row_start,
    int* __restrict__ cntg, int n) {
    __shared__ uint2 ledge[BCAP];
    __shared__ unsigned lcnt[256];
    __shared__ unsigned lws[256];
    __shared__ unsigned ltmp[256];
    __shared__ unsigned lstart[256];
    const int b = blockIdx.x;
    const int t = threadIdx.x;
    lcnt[t] = 0; lws[t] = 0;
    __syncthreads();
    const int e0 = bucket_start[b];
    const int cntE = bucket_tot[b];
    const bool fits = (cntE <= BCAP);
    for (int i = t; i < cntE; i += 256) {
        uint2 r = part[e0 + i];
        if (fits) ledge[i] = r;
        int dlow = (r.x >> 17) & 255;
        atomicAdd(&lcnt[dlow], 1u);
        unsigned wfix = (unsigned)(__uint_as_float(r.y) * WFIX + 0.5f);
        atomicAdd(&lws[dlow], wfix);
    }
    __syncthreads();
    unsigned v = lcnt[t];
    ltmp[t] = v;
    __syncthreads();
    for (int off = 1; off < 256; off <<= 1) {
        unsigned u = (t >= off) ? ltmp[t - off] : 0u;
        __syncthreads();
        ltmp[t] += u;
        __syncthreads();
    }
    lstart[t] = ltmp[t] - v;
    int node = (b << SHIFT) + t;
    if (node < n) {
        row_start[node] = e0 + (int)lstart[t];
        cntg[node] = (int)v;
        float deg = 1.0f + (float)lws[t] * (1.0f / WFIX);
        dis[node] = rsqrtf(deg);
    }
    lcnt[t] = lstart[t];  // reuse as cursor
    __syncthreads();
    for (int i = t; i < cntE; i += 256) {
        uint2 r = fits ? ledge[i] : part[e0 + i];
        int dlow = (r.x >> 17) & 255;
        int pos = e0 + (int)atomicAdd(&lcnt[dlow], 1u);
        csr[pos] = make_uint2(r.x & 0x1FFFFu, r.y);
    }
}

// K4: h = x @ W via bf16 MFMA (16x16x32), bf16 output.
__global__ __launch_bounds__(256) void gemm_mfma(
    const float* __restrict__ x, const unsigned short* __restrict__ wt,
    unsigned short* __restrict__ h, int n) {
    __shared__ unsigned short xs[GBM][136];
    const int row0 = blockIdx.x * GBM;

#pragma unroll
    for (int i = 0; i < 8; ++i) {
        int idx = threadIdx.x + i * 256;
        int r = idx >> 5;
        int c4 = idx & 31;
        int rg = row0 + r;
        float4 v = (rg < n) ? ((const float4*)(x + (size_t)rg * F))[c4]
                            : make_float4(0.f, 0.f, 0.f, 0.f);
        uint2 p;
        p.x = (unsigned)bf16_rne(v.x) | ((unsigned)bf16_rne(v.y) << 16);
        p.y = (unsigned)bf16_rne(v.z) | ((unsigned)bf16_rne(v.w) << 16);
        *(uint2*)&xs[r][c4 * 4] = p;
    }
    __syncthreads();

    const int wid = threadIdx.x >> 6;
    const int lane = threadIdx.x & 63;
    const int l15 = lane & 15;
    const int kg = lane >> 4;
    const int wrow = wid * 16;

    short8 afrag[4];
#pragma unroll
    for (int s = 0; s < 4; ++s)
        afrag[s] = *(const short8*)&xs[wrow + l15][s * 32 + kg * 8];

#pragma unroll
    for (int t = 0; t < 8; ++t) {
        const unsigned short* wb = wt + (size_t)(t * 16 + l15) * F + kg * 8;
        short8 b0 = *(const short8*)(wb);
        short8 b1 = *(const short8*)(wb + 32);
        short8 b2 = *(const short8*)(wb + 64);
        short8 b3 = *(const short8*)(wb + 96);
        f32x4 acc = {0.f, 0.f, 0.f, 0.f};
        acc = __builtin_amdgcn_mfma_f32_16x16x32_bf16(afrag[0], b0, acc, 0, 0, 0);
        acc = __builtin_amdgcn_mfma_f32_16x16x32_bf16(afrag[1], b1, acc, 0, 0, 0);
        acc = __builtin_amdgcn_mfma_f32_16x16x32_bf16(afrag[2], b2, acc, 0, 0, 0);
        acc = __builtin_amdgcn_mfma_f32_16x16x32_bf16(afrag[3], b3, acc, 0, 0, 0);
        int col = t * 16 + l15;
#pragma unroll
        for (int i = 0; i < 4; ++i) {
            int rg = row0 + wrow + kg * 4 + i;
            if (rg < n) h[(size_t)rg * F + col] = bf16_rne(acc[i]);
        }
    }
}

__device__ __forceinline__ void bf16x8_fma(uint4 v, float m, float* acc) {
    union { uint4 u; unsigned short s[8]; } cv;
    cv.u = v;
#pragma unroll
    for (int j = 0; j < 8; ++j) {
        float f = __uint_as_float(((unsigned)cv.s[j]) << 16);
        acc[j] = fmaf(f, m, acc[j]);
    }
}

__device__ __forceinline__ void bf16x8_mul(uint4 v, float m, float* acc) {
    union { uint4 u; unsigned short s[8]; } cv;
    cv.u = v;
#pragma unroll
    for (int j = 0; j < 8; ++j)
        acc[j] = __uint_as_float(((unsigned)cv.s[j]) << 16) * m;
}

// K5: aggregation + fused PairNorm partial stats. Grid-stride, 16-lane group
// per node. Edges processed in batches of 16: the group's lanes cooperatively
// load csr + dis (1 VMEM instr each instead of 16 broadcasts), then the edge
// loop broadcasts idx/nrm via __shfl (DS pipe) and issues h gathers 4-deep.
__global__ __launch_bounds__(256) void aggregate(
    const uint4* __restrict__ h16, const float* __restrict__ dis,
    const float* __restrict__ bias,
    const int* __restrict__ row_start, const int* __restrict__ cntg,
    const uint2* __restrict__ csr, uint4* __restrict__ outb,
    float* __restrict__ part_colsum, float* __restrict__ part_sumsq, int n) {
    const int lane = threadIdx.x & 15;
    const int grp = threadIdx.x >> 4;
    const int gb = (threadIdx.x & 63) & ~15;  // group base lane within wave
    float4 b0 = ((const float4*)bias)[lane * 2];
    float4 b1 = ((const float4*)bias)[lane * 2 + 1];
    const float bb[8] = {b0.x, b0.y, b0.z, b0.w, b1.x, b1.y, b1.z, b1.w};
    float col8[8] = {0, 0, 0, 0, 0, 0, 0, 0};
    float ssq = 0.0f;
    const int gstride = (gridDim.x * 256) >> 4;
    for (int g = (blockIdx.x * 256 + threadIdx.x) >> 4; g < n; g += gstride) {
        float dv = dis[g];
        float acc[8];
        bf16x8_mul(h16[(size_t)g * 16 + lane], dv, acc);
        int e = row_start[g];
        const int e1 = e + cntg[g];
        while (e1 - e >= 16) {
            uint2 r = csr[e + lane];
            unsigned my_idx = r.x;
            float my_nrm = dis[r.x] * __uint_as_float(r.y);
#pragma unroll
            for (int j = 0; j < 16; j += 4) {
                unsigned i0 = (unsigned)__shfl((int)my_idx, gb + j);
                unsigned i1 = (unsigned)__shfl((int)my_idx, gb + j + 1);
                unsigned i2 = (unsigned)__shfl((int)my_idx, gb + j + 2);
                unsigned i3 = (unsigned)__shfl((int)my_idx, gb + j + 3);
                float n0 = __shfl(my_nrm, gb + j);
                float n1 = __shfl(my_nrm, gb + j + 1);
                float n2 = __shfl(my_nrm, gb + j + 2);
                float n3 = __shfl(my_nrm, gb + j + 3);
                uint4 v0 = h16[(size_t)i0 * 16 + lane];
                uint4 v1 = h16[(size_t)i1 * 16 + lane];
                uint4 v2 = h16[(size_t)i2 * 16 + lane];
                uint4 v3 = h16[(size_t)i3 * 16 + lane];
                bf16x8_fma(v0, n0, acc);
                bf16x8_fma(v1, n1, acc);
                bf16x8_fma(v2, n2, acc);
                bf16x8_fma(v3, n3, acc);
            }
            e += 16;
        }
        for (; e + 1 < e1; e += 2) {
            uint2 r0 = csr[e];
            uint2 r1 = csr[e + 1];
            uint4 v0 = h16[(size_t)r0.x * 16 + lane];
            uint4 v1 = h16[(size_t)r1.x * 16 + lane];
            float n0 = dis[r0.x] * __uint_as_float(r0.y);
            float n1 = dis[r1.x] * __uint_as_float(r1.y);
            bf16x8_fma(v0, n0, acc);
            bf16x8_fma(v1, n1, acc);
        }
        if (e < e1) {
            uint2 r0 = csr[e];
            bf16x8_fma(h16[(size_t)r0.x * 16 + lane],
                       dis[r0.x] * __uint_as_float(r0.y), acc);
        }
        float o[8];
        uint4 pk;
        unsigned pw[4];
#pragma unroll
        for (int j = 0; j < 8; ++j) {
            o[j] = fmaf(acc[j], dv, bb[j]);
            col8[j] += o[j];
            ssq = fmaf(o[j], o[j], ssq);
        }
#pragma unroll
        for (int j = 0; j < 4; ++j)
            pw[j] = (unsigned)bf16_rne(o[2 * j]) | ((unsigned)bf16_rne(o[2 * j + 1]) << 16);
        pk.x = pw[0]; pk.y = pw[1]; pk.z = pw[2]; pk.w = pw[3];
        outb[(size_t)g * 16 + lane] = pk;
    }
    __shared__ float red[16][128];
#pragma unroll
    for (int j = 0; j < 8; ++j) red[grp][lane * 8 + j] = col8[j];
    __syncthreads();
    if (threadIdx.x < 128) {
        float s = 0;
#pragma unroll
        for (int g2 = 0; g2 < 16; ++g2) s += red[g2][threadIdx.x];
        part_colsum[(size_t)threadIdx.x * gridDim.x + blockIdx.x] = s;  // transposed
    }
#pragma unroll
    for (int off = 32; off >= 1; off >>= 1) ssq += __shfl_down(ssq, off);
    __shared__ float sss[4];
    if ((threadIdx.x & 63) == 0) sss[threadIdx.x >> 6] = ssq;
    __syncthreads();
    if (threadIdx.x == 0) part_sumsq[blockIdx.x] = sss[0] + sss[1] + sss[2] + sss[3];
}

// K6a: stage-A parallel reduce: 129 blocks. Block j<128 sums column j
// (contiguous nblk floats); block 128 sums part_sumsq.
__global__ __launch_bounds__(256) void reduce_cols(
    const float* __restrict__ part_colsum, const float* __restrict__ part_sumsq,
    float* __restrict__ colsum_tot, float* __restrict__ sumsq_tot, int nblk) {
    const float* src = (blockIdx.x < 128) ? part_colsum + (size_t)blockIdx.x * nblk
                                          : part_sumsq;
    float s = 0.0f;
    for (int i = threadIdx.x; i < nblk; i += 256) s += src[i];
    __shared__ float r[256];
    r[threadIdx.x] = s;
    __syncthreads();
    for (int off = 128; off >= 1; off >>= 1) {
        if (threadIdx.x < off) r[threadIdx.x] += r[threadIdx.x + off];
        __syncthreads();
    }
    if (threadIdx.x == 0) {
        if (blockIdx.x < 128) colsum_tot[blockIdx.x] = r[0];
        else sumsq_tot[0] = r[0];
    }
}

// K7: out = relu((bf16_staging - mean) * invd) -> f32 d_out.
// mean/invd derived in-block from colsum_tot/sumsq_tot (compute_invd fused).
__global__ __launch_bounds__(256) void finalize(const uint4* __restrict__ outb,
                                                float* __restrict__ out,
                                                const float* __restrict__ colsum_tot,
                                                const float* __restrict__ sumsq_tot,
                                                int n) {
    __shared__ float sm[F];
    __shared__ float redl[F];
    __shared__ float siv;
    int t = threadIdx.x;
    float inv_n = 1.0f / (float)n;
    if (t < F) {
        float m = colsum_tot[t] * inv_n;
        sm[t] = m;
        redl[t] = m * m;
    }
    __syncthreads();
    for (int off = 64; off >= 1; off >>= 1) {
        if (t < off) redl[t] += redl[t + off];
        __syncthreads();
    }
    if (t == 0) {
        float ssc = sumsq_tot[0] - (float)n * redl[0];
        if (ssc < 0.0f) ssc = 0.0f;
        siv = PN_SCALE / sqrtf(PN_EPS + ssc * inv_n);
    }
    __syncthreads();
    float iv = siv;
    size_t total = (size_t)n * 16;  // bf16x8 chunks
    size_t i0 = (size_t)blockIdx.x * blockDim.x + threadIdx.x;
    size_t stride = (size_t)gridDim.x * blockDim.x;
    for (size_t i = i0; i < total; i += stride) {
        int c = (int)((i & 15) << 3);  // base col
        uint4 v = outb[i];
        union { uint4 u; unsigned short s[8]; } cv;
        cv.u = v;
        float4 oa, ob;
        float* oo[2] = {&oa.x, &ob.x};
#pragma unroll
        for (int j = 0; j < 8; ++j) {
            float f = __uint_as_float(((unsigned)cv.s[j]) << 16);
            oo[j >> 2][j & 3] = fmaxf(0.0f, (f - sm[c + j]) * iv);
        }
        ((float4*)out)[i * 2] = oa;
        ((float4*)out)[i * 2 + 1] = ob;
    }
}

extern "C" void kernel_launch(void* const* d_in, const int* in_sizes, int n_in,
                              void* d_out, int out_size, void* d_ws, size_t ws_size,
                              hipStream_t stream) {
    const float* x    = (const float*)d_in[0];
    const int*   ei   = (const int*)d_in[1];   // [2, E] int32
    const float* ew   = (const float*)d_in[2];
    const float* W    = (const float*)d_in[3];
    const float* bias = (const float*)d_in[4];
    float* out = (float*)d_out;

    const int n = in_sizes[0] / F;
    const int E = in_sizes[2];
    const int* src = ei;
    const int* dst = ei + E;

    const int nbk = (n + 255) >> SHIFT;          // 391 for n=100000 (<=512)
    const int np2 = (E + CHUNK - 1) / CHUNK;     // 196 for E=1.6M (<=256)

    char* ws = (char*)d_ws;
    size_t off = 0;
    unsigned short* h = (unsigned short*)(ws + off); off += (size_t)n * F * 2;
    unsigned short* ob = (unsigned short*)(ws + off); off += (size_t)n * F * 2;
    uint2* csr = (uint2*)(ws + off);                 off += (size_t)E * 8;
    uint2* part = (uint2*)(ws + off);                off += (size_t)E * 8;
    int* part_cnt = (int*)(ws + off);                off += (size_t)np2 * nbk * 4;
    int* bucket_start = (int*)(ws + off);            off += (size_t)nbk * 4;
    int* bucket_tot = (int*)(ws + off);              off += (size_t)nbk * 4;
    float* dis = (float*)(ws + off);                 off += (size_t)n * 4;
    int* row_start = (int*)(ws + off);               off += (size_t)n * 4;
    int* cntg = (int*)(ws + off);                    off += (size_t)n * 4;
    unsigned short* wt = (unsigned short*)(ws + off); off += (size_t)F * F * 2;
    float* part_colsum = (float*)(ws + off);         off += (size_t)AGG_BLOCKS * 128 * 4;
    float* part_sumsq = (float*)(ws + off);          off += (size_t)AGG_BLOCKS * 4;
    float* colsum_tot = (float*)(ws + off);          off += F * 4;
    float* sumsq_tot = (float*)(ws + off);           off += 4;

    bucket_count<<<np2, 256, 0, stream>>>(dst, part_cnt, W, wt, E, nbk, np2);
    bucket_totk<<<nbk, 256, 0, stream>>>(part_cnt, bucket_tot, np2);
    bucket_startk<<<1, 512, 0, stream>>>(bucket_tot, bucket_start, nbk);
    chunk_bases<<<nbk, 256, 0, stream>>>(part_cnt, bucket_start, np2);
    partition_edges<<<np2, 256, 0, stream>>>(src, dst, ew, part_cnt, part, E, nbk, np2);
    bucket_csr<<<nbk, 256, 0, stream>>>(part, bucket_start, bucket_tot, csr, dis,
                                        row_start, cntg, n);
    gemm_mfma<<<(n + GBM - 1) / GBM, 256, 0, stream>>>(x, wt, h, n);
    aggregate<<<AGG_BLOCKS, 256, 0, stream>>>(
        (const uint4*)h, dis, bias, row_start, cntg, csr, (uint4*)ob,
        part_colsum, part_sumsq, n);
    reduce_cols<<<129, 256, 0, stream>>>(part_colsum, part_sumsq, colsum_tot,
                                         sumsq_tot, AGG_BLOCKS);
    finalize<<<2048, 256, 0, stream>>>((const uint4*)ob, out, colsum_tot, sumsq_tot, n);
}

// Round 11
// 183.568 us; speedup vs baseline: 1.1066x; 1.1066x over previous
//
#include <hip/hip_runtime.h>
#include <hip/hip_bf16.h>
#include <math.h>

#define F 128
#define PN_EPS 1e-5f
#define PN_SCALE 1.0f
#define GBM 64           // rows per block in MFMA GEMM
#define SHIFT 8          // nodes per dst-bucket = 256
#define CHUNK 8192       // edges per partition block
#define WFIX 4194304.0f  // 2^22 fixed-point scale for per-node weight sums
#define AGG_BLOCKS 2048
#define BCAP 6144        // LDS edge staging capacity in bucket_csr (48KB)

using short8 = __attribute__((ext_vector_type(8))) short;
using f32x4  = __attribute__((ext_vector_type(4))) float;

__device__ __forceinline__ unsigned short bf16_rne(float f) {
    union { float f; unsigned u; } v; v.f = f;
    unsigned r = v.u + 0x7fff + ((v.u >> 16) & 1);
    return (unsigned short)(r >> 16);
}

// P1: per-chunk bucket histogram -> part_cnt[bucket][chunk]  (no global atomics).
// First 64 blocks also transpose W -> wt bf16 (fused, saves a launch).
__global__ __launch_bounds__(256) void bucket_count(const int* __restrict__ dst,
                                                    int* __restrict__ part_cnt,
                                                    const float* __restrict__ W,
                                                    unsigned short* __restrict__ wt,
                                                    int E, int nbk, int np2) {
    if (blockIdx.x < 64) {
        int idx = blockIdx.x * 256 + threadIdx.x;  // 0..16383
        int k = idx >> 7;
        int col = idx & 127;
        wt[col * F + k] = bf16_rne(W[idx]);
    }
    __shared__ int lcnt[512];
    for (int i = threadIdx.x; i < nbk; i += 256) lcnt[i] = 0;
    __syncthreads();
    int base = blockIdx.x * CHUNK;
    int end = min(base + CHUNK, E);
    for (int e = base + threadIdx.x; e < end; e += 256)
        atomicAdd(&lcnt[dst[e] >> SHIFT], 1);
    __syncthreads();
    for (int i = threadIdx.x; i < nbk; i += 256)
        part_cnt[(size_t)i * np2 + blockIdx.x] = lcnt[i];  // transposed: [bucket][chunk]
}

// S1: one block per bucket: parallel-reduce its contiguous row -> bucket_tot[b]
__global__ __launch_bounds__(256) void bucket_totk(const int* __restrict__ part_cnt,
                                                   int* __restrict__ bucket_tot, int np2) {
    const int* row = part_cnt + (size_t)blockIdx.x * np2;
    int s = 0;
    for (int i = threadIdx.x; i < np2; i += 256) s += row[i];
    __shared__ int r[256];
    r[threadIdx.x] = s;
    __syncthreads();
    for (int off = 128; off >= 1; off >>= 1) {
        if (threadIdx.x < off) r[threadIdx.x] += r[threadIdx.x + off];
        __syncthreads();
    }
    if (threadIdx.x == 0) bucket_tot[blockIdx.x] = r[0];
}

// S2+S3 merged: one block per bucket. Each block redundantly scans the (small)
// bucket_tot array in LDS to get its own exclusive bucket start (1.5KB L2-hit),
// writes bucket_start[b], then LDS-scans its chunk-count row into write bases.
__global__ __launch_bounds__(256) void chunk_bases(int* __restrict__ part_cnt,
                                                   const int* __restrict__ bucket_tot,
                                                   int* __restrict__ bucket_start,
                                                   int np2, int nbk) {
    __shared__ int bs[512];
    const int b = blockIdx.x;
    const int t = threadIdx.x;
    // load totals (nbk <= 512), 2 elems/thread
    for (int i = t; i < 512; i += 256) bs[i] = (i < nbk) ? bucket_tot[i] : 0;
    __syncthreads();
    // Hillis-Steele inclusive scan over 512 entries, 2 elems/thread
    for (int off = 1; off < 512; off <<= 1) {
        int i0 = t, i1 = t + 256;
        int v0 = (i0 >= off) ? bs[i0 - off] : 0;
        int v1 = (i1 >= off) ? bs[i1 - off] : 0;
        __syncthreads();
        bs[i0] += v0;
        bs[i1] += v1;
        __syncthreads();
    }
    const int my_start = (b == 0) ? 0 : bs[b - 1];
    if (t == 0) bucket_start[b] = my_start;
    __syncthreads();
    // exclusive scan of this bucket's chunk-count row (np2 <= 256)
    __shared__ int s[256];
    int* row = part_cnt + (size_t)b * np2;
    int v = (t < np2) ? row[t] : 0;
    s[t] = v;
    __syncthreads();
    for (int off = 1; off < 256; off <<= 1) {
        int u = (t >= off) ? s[t - off] : 0;
        __syncthreads();
        s[t] += u;
        __syncthreads();
    }
    if (t < np2) row[t] = my_start + s[t] - v;
}

// P2: partition edges into bucket-contiguous part[] = {src | dlow<<17, w_bits}
__global__ __launch_bounds__(256) void partition_edges(
    const int* __restrict__ src, const int* __restrict__ dst,
    const float* __restrict__ ew, const int* __restrict__ part_cnt,
    uint2* __restrict__ part, int E, int nbk, int np2) {
    __shared__ int cur[512];
    for (int i = threadIdx.x; i < nbk; i += 256)
        cur[i] = part_cnt[(size_t)i * np2 + blockIdx.x];
    __syncthreads();
    int base = blockIdx.x * CHUNK;
    int end = min(base + CHUNK, E);
    for (int e = base + threadIdx.x; e < end; e += 256) {
        int d = dst[e];
        int b = d >> SHIFT;
        int pos = atomicAdd(&cur[b], 1);
        part[pos] = make_uint2((unsigned)src[e] | ((unsigned)(d & 255) << 17),
                               __float_as_uint(ew[e]));
    }
}

// P3: one block per bucket. Edges staged in LDS (single global read), per-node
// count + weight-sum via LDS atomics, LDS scan -> row_start/cnt/dis, scatter
// from LDS to csr={src, w}. Fallback to 2-pass global path if bucket > BCAP.
__global__ __launch_bounds__(256) void bucket_csr(
    const uint2* __restrict__ part, const int* __restrict__ bucket_start,
    const int* __restrict__ bucket_tot, uint2* __restrict__ csr,
    float* __restrict__ dis, int* __restrict__ row_start,
    int* __restrict__ cntg, int n) {
    __shared__ uint2 ledge[BCAP];
    __shared__ unsigned lcnt[256];
    __shared__ unsigned lws[256];
    __shared__ unsigned ltmp[256];
    __shared__ unsigned lstart[256];
    const int b = blockIdx.x;
    const int t = threadIdx.x;
    lcnt[t] = 0; lws[t] = 0;
    __syncthreads();
    const int e0 = bucket_start[b];
    const int cntE = bucket_tot[b];
    const bool fits = (cntE <= BCAP);
    for (int i = t; i < cntE; i += 256) {
        uint2 r = part[e0 + i];
        if (fits) ledge[i] = r;
        int dlow = (r.x >> 17) & 255;
        atomicAdd(&lcnt[dlow], 1u);
        unsigned wfix = (unsigned)(__uint_as_float(r.y) * WFIX + 0.5f);
        atomicAdd(&lws[dlow], wfix);
    }
    __syncthreads();
    unsigned v = lcnt[t];
    ltmp[t] = v;
    __syncthreads();
    for (int off = 1; off < 256; off <<= 1) {
        unsigned u = (t >= off) ? ltmp[t - off] : 0u;
        __syncthreads();
        ltmp[t] += u;
        __syncthreads();
    }
    lstart[t] = ltmp[t] - v;
    int node = (b << SHIFT) + t;
    if (node < n) {
        row_start[node] = e0 + (int)lstart[t];
        cntg[node] = (int)v;
        float deg = 1.0f + (float)lws[t] * (1.0f / WFIX);
        dis[node] = rsqrtf(deg);
    }
    lcnt[t] = lstart[t];  // reuse as cursor
    __syncthreads();
    for (int i = t; i < cntE; i += 256) {
        uint2 r = fits ? ledge[i] : part[e0 + i];
        int dlow = (r.x >> 17) & 255;
        int pos = e0 + (int)atomicAdd(&lcnt[dlow], 1u);
        csr[pos] = make_uint2(r.x & 0x1FFFFu, r.y);
    }
}

// K4: h = x @ W via bf16 MFMA (16x16x32), bf16 output.
__global__ __launch_bounds__(256) void gemm_mfma(
    const float* __restrict__ x, const unsigned short* __restrict__ wt,
    unsigned short* __restrict__ h, int n) {
    __shared__ unsigned short xs[GBM][136];
    const int row0 = blockIdx.x * GBM;

#pragma unroll
    for (int i = 0; i < 8; ++i) {
        int idx = threadIdx.x + i * 256;
        int r = idx >> 5;
        int c4 = idx & 31;
        int rg = row0 + r;
        float4 v = (rg < n) ? ((const float4*)(x + (size_t)rg * F))[c4]
                            : make_float4(0.f, 0.f, 0.f, 0.f);
        uint2 p;
        p.x = (unsigned)bf16_rne(v.x) | ((unsigned)bf16_rne(v.y) << 16);
        p.y = (unsigned)bf16_rne(v.z) | ((unsigned)bf16_rne(v.w) << 16);
        *(uint2*)&xs[r][c4 * 4] = p;
    }
    __syncthreads();

    const int wid = threadIdx.x >> 6;
    const int lane = threadIdx.x & 63;
    const int l15 = lane & 15;
    const int kg = lane >> 4;
    const int wrow = wid * 16;

    short8 afrag[4];
#pragma unroll
    for (int s = 0; s < 4; ++s)
        afrag[s] = *(const short8*)&xs[wrow + l15][s * 32 + kg * 8];

#pragma unroll
    for (int t = 0; t < 8; ++t) {
        const unsigned short* wb = wt + (size_t)(t * 16 + l15) * F + kg * 8;
        short8 b0 = *(const short8*)(wb);
        short8 b1 = *(const short8*)(wb + 32);
        short8 b2 = *(const short8*)(wb + 64);
        short8 b3 = *(const short8*)(wb + 96);
        f32x4 acc = {0.f, 0.f, 0.f, 0.f};
        acc = __builtin_amdgcn_mfma_f32_16x16x32_bf16(afrag[0], b0, acc, 0, 0, 0);
        acc = __builtin_amdgcn_mfma_f32_16x16x32_bf16(afrag[1], b1, acc, 0, 0, 0);
        acc = __builtin_amdgcn_mfma_f32_16x16x32_bf16(afrag[2], b2, acc, 0, 0, 0);
        acc = __builtin_amdgcn_mfma_f32_16x16x32_bf16(afrag[3], b3, acc, 0, 0, 0);
        int col = t * 16 + l15;
#pragma unroll
        for (int i = 0; i < 4; ++i) {
            int rg = row0 + wrow + kg * 4 + i;
            if (rg < n) h[(size_t)rg * F + col] = bf16_rne(acc[i]);
        }
    }
}

__device__ __forceinline__ void bf16x8_fma(uint4 v, float m, float* acc) {
    union { uint4 u; unsigned short s[8]; } cv;
    cv.u = v;
#pragma unroll
    for (int j = 0; j < 8; ++j) {
        float f = __uint_as_float(((unsigned)cv.s[j]) << 16);
        acc[j] = fmaf(f, m, acc[j]);
    }
}

__device__ __forceinline__ void bf16x8_mul(uint4 v, float m, float* acc) {
    union { uint4 u; unsigned short s[8]; } cv;
    cv.u = v;
#pragma unroll
    for (int j = 0; j < 8; ++j)
        acc[j] = __uint_as_float(((unsigned)cv.s[j]) << 16) * m;
}

// K5: aggregation + fused PairNorm partial stats. Grid-stride, 16-lane group
// per node, 2-deep gather unroll. VGPR ~32 / occupancy ~72% is the proven
// sweet spot (R8 4-deep and R10 shfl-batch both regressed via VGPR pressure).
// Pre-norm output written as BF16 staging; stats in f32.
__global__ __launch_bounds__(256) void aggregate(
    const uint4* __restrict__ h16, const float* __restrict__ dis,
    const float* __restrict__ bias,
    const int* __restrict__ row_start, const int* __restrict__ cntg,
    const uint2* __restrict__ csr, uint4* __restrict__ outb,
    float* __restrict__ part_colsum, float* __restrict__ part_sumsq, int n) {
    const int lane = threadIdx.x & 15;
    const int grp = threadIdx.x >> 4;
    float4 b0 = ((const float4*)bias)[lane * 2];
    float4 b1 = ((const float4*)bias)[lane * 2 + 1];
    const float bb[8] = {b0.x, b0.y, b0.z, b0.w, b1.x, b1.y, b1.z, b1.w};
    float col8[8] = {0, 0, 0, 0, 0, 0, 0, 0};
    float ssq = 0.0f;
    const int gstride = (gridDim.x * 256) >> 4;
    for (int g = (blockIdx.x * 256 + threadIdx.x) >> 4; g < n; g += gstride) {
        float dv = dis[g];
        float acc[8];
        bf16x8_mul(h16[(size_t)g * 16 + lane], dv, acc);
        int e = row_start[g];
        const int e1 = e + cntg[g];
        for (; e + 1 < e1; e += 2) {
            uint2 r0 = csr[e];
            uint2 r1 = csr[e + 1];
            uint4 v0 = h16[(size_t)r0.x * 16 + lane];
            uint4 v1 = h16[(size_t)r1.x * 16 + lane];
            float n0 = dis[r0.x] * __uint_as_float(r0.y);
            float n1 = dis[r1.x] * __uint_as_float(r1.y);
            bf16x8_fma(v0, n0, acc);
            bf16x8_fma(v1, n1, acc);
        }
        if (e < e1) {
            uint2 r0 = csr[e];
            bf16x8_fma(h16[(size_t)r0.x * 16 + lane],
                       dis[r0.x] * __uint_as_float(r0.y), acc);
        }
        float o[8];
        uint4 pk;
        unsigned pw[4];
#pragma unroll
        for (int j = 0; j < 8; ++j) {
            o[j] = fmaf(acc[j], dv, bb[j]);
            col8[j] += o[j];
            ssq = fmaf(o[j], o[j], ssq);
        }
#pragma unroll
        for (int j = 0; j < 4; ++j)
            pw[j] = (unsigned)bf16_rne(o[2 * j]) | ((unsigned)bf16_rne(o[2 * j + 1]) << 16);
        pk.x = pw[0]; pk.y = pw[1]; pk.z = pw[2]; pk.w = pw[3];
        outb[(size_t)g * 16 + lane] = pk;
    }
    __shared__ float red[16][128];
#pragma unroll
    for (int j = 0; j < 8; ++j) red[grp][lane * 8 + j] = col8[j];
    __syncthreads();
    if (threadIdx.x < 128) {
        float s = 0;
#pragma unroll
        for (int g2 = 0; g2 < 16; ++g2) s += red[g2][threadIdx.x];
        part_colsum[(size_t)threadIdx.x * gridDim.x + blockIdx.x] = s;  // transposed
    }
#pragma unroll
    for (int off = 32; off >= 1; off >>= 1) ssq += __shfl_down(ssq, off);
    __shared__ float sss[4];
    if ((threadIdx.x & 63) == 0) sss[threadIdx.x >> 6] = ssq;
    __syncthreads();
    if (threadIdx.x == 0) part_sumsq[blockIdx.x] = sss[0] + sss[1] + sss[2] + sss[3];
}

// K6a: stage-A parallel reduce: 129 blocks. Block j<128 sums column j
// (contiguous nblk floats); block 128 sums part_sumsq.
__global__ __launch_bounds__(256) void reduce_cols(
    const float* __restrict__ part_colsum, const float* __restrict__ part_sumsq,
    float* __restrict__ colsum_tot, float* __restrict__ sumsq_tot, int nblk) {
    const float* src = (blockIdx.x < 128) ? part_colsum + (size_t)blockIdx.x * nblk
                                          : part_sumsq;
    float s = 0.0f;
    for (int i = threadIdx.x; i < nblk; i += 256) s += src[i];
    __shared__ float r[256];
    r[threadIdx.x] = s;
    __syncthreads();
    for (int off = 128; off >= 1; off >>= 1) {
        if (threadIdx.x < off) r[threadIdx.x] += r[threadIdx.x + off];
        __syncthreads();
    }
    if (threadIdx.x == 0) {
        if (blockIdx.x < 128) colsum_tot[blockIdx.x] = r[0];
        else sumsq_tot[0] = r[0];
    }
}

// K7: out = relu((bf16_staging - mean) * invd) -> f32 d_out.
// mean/invd derived in-block from colsum_tot/sumsq_tot.
__global__ __launch_bounds__(256) void finalize(const uint4* __restrict__ outb,
                                                float* __restrict__ out,
                                                const float* __restrict__ colsum_tot,
                                                const float* __restrict__ sumsq_tot,
                                                int n) {
    __shared__ float sm[F];
    __shared__ float redl[F];
    __shared__ float siv;
    int t = threadIdx.x;
    float inv_n = 1.0f / (float)n;
    if (t < F) {
        float m = colsum_tot[t] * inv_n;
        sm[t] = m;
        redl[t] = m * m;
    }
    __syncthreads();
    for (int off = 64; off >= 1; off >>= 1) {
        if (t < off) redl[t] += redl[t + off];
        __syncthreads();
    }
    if (t == 0) {
        float ssc = sumsq_tot[0] - (float)n * redl[0];
        if (ssc < 0.0f) ssc = 0.0f;
        siv = PN_SCALE / sqrtf(PN_EPS + ssc * inv_n);
    }
    __syncthreads();
    float iv = siv;
    size_t total = (size_t)n * 16;  // bf16x8 chunks
    size_t i0 = (size_t)blockIdx.x * blockDim.x + threadIdx.x;
    size_t stride = (size_t)gridDim.x * blockDim.x;
    for (size_t i = i0; i < total; i += stride) {
        int c = (int)((i & 15) << 3);  // base col
        uint4 v = outb[i];
        union { uint4 u; unsigned short s[8]; } cv;
        cv.u = v;
        float4 oa, ob;
        float* oo[2] = {&oa.x, &ob.x};
#pragma unroll
        for (int j = 0; j < 8; ++j) {
            float f = __uint_as_float(((unsigned)cv.s[j]) << 16);
            oo[j >> 2][j & 3] = fmaxf(0.0f, (f - sm[c + j]) * iv);
        }
        ((float4*)out)[i * 2] = oa;
        ((float4*)out)[i * 2 + 1] = ob;
    }
}

extern "C" void kernel_launch(void* const* d_in, const int* in_sizes, int n_in,
                              void* d_out, int out_size, void* d_ws, size_t ws_size,
                              hipStream_t stream) {
    const float* x    = (const float*)d_in[0];
    const int*   ei   = (const int*)d_in[1];   // [2, E] int32
    const float* ew   = (const float*)d_in[2];
    const float* W    = (const float*)d_in[3];
    const float* bias = (const float*)d_in[4];
    float* out = (float*)d_out;

    const int n = in_sizes[0] / F;
    const int E = in_sizes[2];
    const int* src = ei;
    const int* dst = ei + E;

    const int nbk = (n + 255) >> SHIFT;          // 391 for n=100000 (<=512)
    const int np2 = (E + CHUNK - 1) / CHUNK;     // 196 for E=1.6M (<=256)

    char* ws = (char*)d_ws;
    size_t off = 0;
    unsigned short* h = (unsigned short*)(ws + off); off += (size_t)n * F * 2;
    unsigned short* ob = (unsigned short*)(ws + off); off += (size_t)n * F * 2;
    uint2* csr = (uint2*)(ws + off);                 off += (size_t)E * 8;
    uint2* part = (uint2*)(ws + off);                off += (size_t)E * 8;
    int* part_cnt = (int*)(ws + off);                off += (size_t)np2 * nbk * 4;
    int* bucket_start = (int*)(ws + off);            off += (size_t)nbk * 4;
    int* bucket_tot = (int*)(ws + off);              off += (size_t)nbk * 4;
    float* dis = (float*)(ws + off);                 off += (size_t)n * 4;
    int* row_start = (int*)(ws + off);               off += (size_t)n * 4;
    int* cntg = (int*)(ws + off);                    off += (size_t)n * 4;
    unsigned short* wt = (unsigned short*)(ws + off); off += (size_t)F * F * 2;
    float* part_colsum = (float*)(ws + off);         off += (size_t)AGG_BLOCKS * 128 * 4;
    float* part_sumsq = (float*)(ws + off);          off += (size_t)AGG_BLOCKS * 4;
    float* colsum_tot = (float*)(ws + off);          off += F * 4;
    float* sumsq_tot = (float*)(ws + off);           off += 4;

    bucket_count<<<np2, 256, 0, stream>>>(dst, part_cnt, W, wt, E, nbk, np2);
    bucket_totk<<<nbk, 256, 0, stream>>>(part_cnt, bucket_tot, np2);
    chunk_bases<<<nbk, 256, 0, stream>>>(part_cnt, bucket_tot, bucket_start, np2, nbk);
    partition_edges<<<np2, 256, 0, stream>>>(src, dst, ew, part_cnt, part, E, nbk, np2);
    bucket_csr<<<nbk, 256, 0, stream>>>(part, bucket_start, bucket_tot, csr, dis,
                                        row_start, cntg, n);
    gemm_mfma<<<(n + GBM - 1) / GBM, 256, 0, stream>>>(x, wt, h, n);
    aggregate<<<AGG_BLOCKS, 256, 0, stream>>>(
        (const uint4*)h, dis, bias, row_start, cntg, csr, (uint4*)ob,
        part_colsum, part_sumsq, n);
    reduce_cols<<<129, 256, 0, stream>>>(part_colsum, part_sumsq, colsum_tot,
                                         sumsq_tot, AGG_BLOCKS);
    finalize<<<2048, 256, 0, stream>>>((const uint4*)ob, out, colsum_tot, sumsq_tot, n);
}